// Round 14
// baseline (123.959 us; speedup 1.0000x reference)
//
#include <hip/hip_runtime.h>
#include <math.h>

#define BB 64
#define QQ 900
#define NN 30
#define C1 1001
#define QN (QQ * NN)
#define NO_OBJ_W 0.1f
#define MTB 512                 // fused back-end block size (8 waves)
#define LDW 31                  // padded LDS row stride (2-way banks = free)

// ---- persistent device scratch (fully rewritten every call) ----
__device__ unsigned g_ord[BB * QN];   // order-mapped cost keys [b][q][t]
__device__ float  g_logZ[BB * QQ];
__device__ float  g_noobj[BB * QQ];
__device__ float4 g_xyxy[BB * QQ];
__device__ float  g_acc[3];
__device__ unsigned g_cnt;

__device__ __forceinline__ float giou_f(float ax1, float ay1, float ax2, float ay2,
                                        float bx1, float by1, float bx2, float by2) {
    float ix1 = fmaxf(ax1, bx1), iy1 = fmaxf(ay1, by1);
    float ix2 = fminf(ax2, bx2), iy2 = fminf(ay2, by2);
    float iw = fmaxf(ix2 - ix1, 0.f), ih = fmaxf(iy2 - iy1, 0.f);
    float inter = iw * ih;
    float areaA = fmaxf(ax2 - ax1, 0.f) * fmaxf(ay2 - ay1, 0.f);
    float areaB = fmaxf(bx2 - bx1, 0.f) * fmaxf(by2 - by1, 0.f);
    float uni = areaA + areaB - inter;
    float iou = inter / fmaxf(uni, 1e-6f);
    float cx1 = fminf(ax1, bx1), cy1 = fminf(ay1, by1);
    float cx2 = fmaxf(ax2, bx2), cy2 = fmaxf(ay2, by2);
    float cw = fmaxf(cx2 - cx1, 0.f), ch = fmaxf(cy2 - cy1, 0.f);
    float ac = cw * ch;
    return iou - (ac - uni) / fmaxf(ac, 1e-6f);
}

__device__ __forceinline__ unsigned ord_map(float f) {
    unsigned u = __float_as_uint(f);
    return (u & 0x80000000u) ? ~u : (u | 0x80000000u);   // order-preserving map
}

// ---- K1: per-query softmax + contiguous ord-key write (+ acc reset) ----
__global__ __launch_bounds__(256) void cost_kernel(const float* __restrict__ logits,
                                                   const float* __restrict__ pboxes,
                                                   const int*   __restrict__ labels,
                                                   const float* __restrict__ tboxes) {
    if (blockIdx.x == 0 && threadIdx.x == 0) {
        g_acc[0] = 0.f; g_acc[1] = 0.f; g_acc[2] = 0.f;
        g_cnt = 0u;
    }
    int gwave = (blockIdx.x * blockDim.x + threadIdx.x) >> 6;
    int lane = threadIdx.x & 63;
    if (gwave >= BB * QQ) return;
    int b = gwave / QQ;

    size_t s = (size_t)gwave * C1;
    size_t a0 = (s + 3) >> 2;
    size_t a1 = (s + C1) >> 2;
    int nq = (int)(a1 - a0);
    int hh = (int)(a0 * 4 - s);
    int tt = (int)((s + C1) - a1 * 4);
    const float4* L4 = (const float4*)logits;

    float4 v4[4];
#pragma unroll
    for (int i = 0; i < 4; ++i) {
        int qq = lane + 64 * i;
        v4[i] = (qq < nq) ? L4[a0 + qq]
                          : make_float4(-INFINITY, -INFINITY, -INFINITY, -INFINITY);
    }
    float e1 = (lane < hh) ? logits[s + lane] : -INFINITY;
    float e2 = (lane < tt) ? logits[a1 * 4 + lane] : -INFINITY;

    float mx = fmaxf(e1, e2);
#pragma unroll
    for (int i = 0; i < 4; ++i)
        mx = fmaxf(mx, fmaxf(fmaxf(v4[i].x, v4[i].y), fmaxf(v4[i].z, v4[i].w)));
#pragma unroll
    for (int off = 32; off; off >>= 1) mx = fmaxf(mx, __shfl_xor(mx, off));

    float sm = __expf(e1 - mx) + __expf(e2 - mx);
#pragma unroll
    for (int i = 0; i < 4; ++i) {
        sm += __expf(v4[i].x - mx);
        sm += __expf(v4[i].y - mx);
        sm += __expf(v4[i].z - mx);
        sm += __expf(v4[i].w - mx);
    }
#pragma unroll
    for (int off = 32; off; off >>= 1) sm += __shfl_xor(sm, off);
    float logZ = mx + __logf(sm);

    float row1000 = logits[s + 1000];

    const float* pb = pboxes + (size_t)gwave * 4;
    float cx = pb[0], cy = pb[1], w = pb[2], h = pb[3];
    float x1 = fminf(fmaxf(cx - 0.5f * w, 0.f), 1.f);
    float y1 = fminf(fmaxf(cy - 0.5f * h, 0.f), 1.f);
    float x2 = fminf(fmaxf(cx + 0.5f * w, 0.f), 1.f);
    float y2 = fminf(fmaxf(cy + 0.5f * h, 0.f), 1.f);

    if (lane == 0) {
        g_logZ[gwave] = logZ;
        g_noobj[gwave] = logZ - row1000;
        g_xyxy[gwave] = make_float4(x1, y1, x2, y2);
    }

    if (lane < NN) {
        int t = lane;
        int lab = labels[b * NN + t];
        float pcls = __expf(logits[s + lab] - logZ);
        const float* tb = tboxes + ((size_t)(b * NN + t)) * 4;
        float tx1 = tb[0], ty1 = tb[1], tx2 = tb[2], ty2 = tb[3];
        float l1 = fabsf(x1 - tx1) + fabsf(y1 - ty1) + fabsf(x2 - tx2) + fabsf(y2 - ty2);
        float g = giou_f(x1, y1, x2, y2, tx1, ty1, tx2, ty2);
        g_ord[(size_t)gwave * NN + t] = ord_map(-pcls + 5.0f * l1 - 2.0f * g);
    }
}

// ---- K2: fused select + match + loss, ONE BLOCK PER BATCH (512 thr) ----
// stage batch ord-matrix into LDS (coalesced uint4, stride-31 rows) ->
// 8 waves bitonic-sort+pop-2 extract 30 columns from LDS -> wave0 match ->
// 512-thread loss -> device atomic reduce (last block writes out).
__global__ __launch_bounds__(MTB, 1) void sml_kernel(const float* __restrict__ logits,
                                                     const int*   __restrict__ labels,
                                                     const float* __restrict__ tboxes,
                                                     float* __restrict__ out) {
    int b = blockIdx.x;
    int tid = threadIdx.x;
    int lane = tid & 63, wid = tid >> 6;

    __shared__ unsigned s_ord[QQ * LDW];             // 111.6 KB
    __shared__ unsigned long long s_cand[NN * NN];   // 7.2 KB
    __shared__ int s_pi[NN], s_ti[NN];
    __shared__ unsigned s_dead[29];
    __shared__ float s4[MTB / 64][4];

    // --- stage: coalesced uint4 read -> stride-31 LDS rows ---
    const uint4* src4 = (const uint4*)(g_ord + (size_t)b * QN);   // QN/4 = 6750
    for (int i = tid; i < QN / 4; i += MTB) {
        uint4 v = src4[i];
        int f = 4 * i;
        int q = f / NN, t = f - q * NN;    // 30 | f only when t==0.. general split:
        // elements f..f+3 may cross a row boundary; handle each
        unsigned vals[4] = {v.x, v.y, v.z, v.w};
#pragma unroll
        for (int k = 0; k < 4; ++k) {
            int fk = f + k;
            int qk = fk / NN, tk = fk - qk * NN;
            s_ord[qk * LDW + tk] = vals[k];
        }
    }
    __syncthreads();

    // --- select: per wave, columns c = wid, wid+8, ... ---
    for (int c = wid; c < NN; c += MTB / 64) {
        unsigned long long key[16];
        if (lane < 60) {
#pragma unroll
            for (int j = 0; j < 15; ++j) {
                int q = j * 60 + lane;
                unsigned o = s_ord[q * LDW + c];
                key[j] = ((unsigned long long)o << 32) | (unsigned)(q * NN + c);
            }
        } else {
#pragma unroll
            for (int j = 0; j < 15; ++j) key[j] = ~0ull;
        }
        key[15] = ~0ull;

        // bitonic sort 16 ascending, fully static indices
#pragma unroll
        for (int kk = 2; kk <= 16; kk <<= 1) {
#pragma unroll
            for (int jj = kk >> 1; jj > 0; jj >>= 1) {
#pragma unroll
                for (int i = 0; i < 16; ++i) {
                    int l = i ^ jj;
                    if (l > i) {
                        bool up = ((i & kk) == 0);
                        unsigned long long a = key[i], cc = key[l];
                        bool sw = up ? (a > cc) : (a < cc);
                        key[i] = sw ? cc : a;
                        key[l] = sw ? a : cc;
                    }
                }
            }
        }

        // pop-2 extraction: 15 rounds of top-2 merging wave reduce
#pragma unroll 1
        for (int r = 0; r < NN / 2; ++r) {
            unsigned long long m1 = key[0];
            unsigned long long m2 = key[1];
#pragma unroll
            for (int off = 32; off; off >>= 1) {
                unsigned long long o1 = __shfl_xor(m1, off);
                unsigned long long o2 = __shfl_xor(m2, off);
                unsigned long long lo = (o1 < m1) ? o1 : m1;
                unsigned long long hi = (o1 < m1) ? m1 : o1;
                unsigned long long n2 = (o2 < m2) ? o2 : m2;
                m1 = lo;
                m2 = (hi < n2) ? hi : n2;
            }
            if (lane == 2 * r)     s_cand[c * NN + 2 * r]     = m1;
            if (lane == 2 * r + 1) s_cand[c * NN + 2 * r + 1] = m2;
            if (key[0] == m1 || key[0] == m2) {
#pragma unroll
                for (int j = 0; j < 15; ++j) key[j] = key[j + 1];
                key[15] = ~0ull;
            }
            if (key[0] == m2) {
#pragma unroll
                for (int j = 0; j < 15; ++j) key[j] = key[j + 1];
                key[15] = ~0ull;
            }
        }
    }
    if (tid < 29) s_dead[tid] = 0u;
    __syncthreads();

    // --- match: wave 0, greedy pop-1-or-2 on the 30 sorted lists ---
    if (tid < 64) {
        bool colLive = lane < NN;
        int ptr = 0;
        unsigned long long cand = colLive ? s_cand[lane * NN] : ~0ull;
        unsigned rowc = colLive ? ((unsigned)cand) / NN : 0u;

        int it = 0;
        while (it < NN) {
            unsigned long long m1 = colLive ? cand : ~0ull;
            unsigned long long m2 = ~0ull;
#pragma unroll
            for (int off = 32; off; off >>= 1) {
                unsigned long long o1 = __shfl_xor(m1, off);
                unsigned long long o2 = __shfl_xor(m2, off);
                unsigned long long lo = (o1 < m1) ? o1 : m1;
                unsigned long long hi = (o1 < m1) ? m1 : o1;
                unsigned long long n2 = (o2 < m2) ? o2 : m2;
                m1 = lo;
                m2 = (hi < n2) ? hi : n2;
            }
            unsigned e1 = (unsigned)m1;
            int q1 = e1 / NN, t1 = e1 - (e1 / NN) * NN;
            unsigned e2 = (unsigned)m2;
            int q2 = e2 / NN, t2 = e2 - (e2 / NN) * NN;
            bool acc2 = (m2 != ~0ull) && (it + 1 < NN) && (q2 != q1) && (t2 != t1);

            if (lane == 0) {
                s_pi[it] = q1;
                s_ti[it] = t1;
                s_dead[q1 >> 5] |= (1u << (q1 & 31));
                if (acc2) {
                    s_pi[it + 1] = q2;
                    s_ti[it + 1] = t2;
                    s_dead[q2 >> 5] |= (1u << (q2 & 31));
                }
            }
            if (lane == t1) colLive = false;
            if (acc2 && lane == t2) colLive = false;
            if (colLive && (rowc == (unsigned)q1 || (acc2 && rowc == (unsigned)q2))) {
                do {
                    ++ptr;
                    cand = s_cand[lane * NN + ptr];
                    rowc = ((unsigned)cand) / NN;
                } while ((s_dead[rowc >> 5] >> (rowc & 31)) & 1u);
            }
            it += acc2 ? 2 : 1;
        }
    }
    __syncthreads();

    // --- loss: CE algebra (per-batch denom == 117 exactly) ---
    float sA = 0.f;
    for (int q = tid; q < QQ; q += MTB) sA += g_noobj[b * QQ + q];

    float sB = 0.f, sL = 0.f, sG = 0.f;
    if (tid < NN) {
        int pq = s_pi[tid], pt = s_ti[tid];
        int gq = b * QQ + pq;
        int lab = labels[b * NN + pt];
        float mnll = g_logZ[gq] - logits[(size_t)gq * C1 + lab];
        sB = mnll - NO_OBJ_W * g_noobj[gq];
        float4 p = g_xyxy[gq];
        const float* tb = tboxes + ((size_t)(b * NN + pt)) * 4;
        float tx1 = tb[0], ty1 = tb[1], tx2 = tb[2], ty2 = tb[3];
        sL = fabsf(p.x - tx1) + fabsf(p.y - ty1) + fabsf(p.z - tx2) + fabsf(p.w - ty2);
        sG = 1.0f - giou_f(p.x, p.y, p.z, p.w, tx1, ty1, tx2, ty2);
    }

    float vv[4] = {sA, sB, sL, sG};
#pragma unroll
    for (int j = 0; j < 4; ++j) {
        float x = vv[j];
#pragma unroll
        for (int off = 32; off; off >>= 1) x += __shfl_xor(x, off);
        if (lane == 0) s4[wid][j] = x;
    }
    __syncthreads();
    if (tid == 0) {
        float a = 0.f, bs = 0.f, l = 0.f, g = 0.f;
        for (int w = 0; w < MTB / 64; ++w) {
            a += s4[w][0]; bs += s4[w][1]; l += s4[w][2]; g += s4[w][3];
        }
        atomicAdd(&g_acc[0], NO_OBJ_W * a + bs);
        atomicAdd(&g_acc[1], l);
        atomicAdd(&g_acc[2], g);
        __threadfence();
        unsigned prev = atomicAdd(&g_cnt, 1u);
        if (prev == BB - 1) {   // last block finalizes
            __threadfence();
            float ce = atomicAdd(&g_acc[0], 0.f) / (float)(BB * 117);
            float l1 = atomicAdd(&g_acc[1], 0.f) / (float)(BB * NN * 4);
            float gl = atomicAdd(&g_acc[2], 0.f) / (float)(BB * NN);
            out[0] = ce + 5.0f * l1 + 2.0f * gl;
            out[1] = ce;
            out[2] = l1;
            out[3] = gl;
        }
    }
}

extern "C" void kernel_launch(void* const* d_in, const int* in_sizes, int n_in,
                              void* d_out, int out_size, void* d_ws, size_t ws_size,
                              hipStream_t stream) {
    const float* pred_logits = (const float*)d_in[0];
    const float* pred_boxes  = (const float*)d_in[1];
    const int*   tgt_labels  = (const int*)d_in[2];
    const float* tgt_boxes   = (const float*)d_in[3];
    float* out = (float*)d_out;

    cost_kernel<<<(BB * QQ) / 4, 256, 0, stream>>>(pred_logits, pred_boxes, tgt_labels, tgt_boxes);
    sml_kernel<<<BB, MTB, 0, stream>>>(pred_logits, tgt_labels, tgt_boxes, out);
}

// Round 15
// 93.355 us; speedup vs baseline: 1.3278x; 1.3278x over previous
//
#include <hip/hip_runtime.h>
#include <math.h>

#define BB 64
#define QQ 900
#define NN 30
#define C1 1001
#define QN (QQ * NN)
#define NO_OBJ_W 0.1f

// ---- persistent device scratch (fully rewritten every call) ----
__device__ __align__(16) unsigned g_ordT[BB * NN * QQ];  // ord keys TRANSPOSED [b][t][q]
__device__ unsigned long long g_top[BB * NN * NN];       // per-column sorted top-30
__device__ float  g_logZ[BB * QQ];
__device__ float  g_noobj[BB * QQ];
__device__ float4 g_xyxy[BB * QQ];
__device__ float  g_acc[3];
__device__ unsigned g_cnt;

__device__ __forceinline__ float giou_f(float ax1, float ay1, float ax2, float ay2,
                                        float bx1, float by1, float bx2, float by2) {
    float ix1 = fmaxf(ax1, bx1), iy1 = fmaxf(ay1, by1);
    float ix2 = fminf(ax2, bx2), iy2 = fminf(ay2, by2);
    float iw = fmaxf(ix2 - ix1, 0.f), ih = fmaxf(iy2 - iy1, 0.f);
    float inter = iw * ih;
    float areaA = fmaxf(ax2 - ax1, 0.f) * fmaxf(ay2 - ay1, 0.f);
    float areaB = fmaxf(bx2 - bx1, 0.f) * fmaxf(by2 - by1, 0.f);
    float uni = areaA + areaB - inter;
    float iou = inter / fmaxf(uni, 1e-6f);
    float cx1 = fminf(ax1, bx1), cy1 = fminf(ay1, by1);
    float cx2 = fmaxf(ax2, bx2), cy2 = fmaxf(ay2, by2);
    float cw = fmaxf(cx2 - cx1, 0.f), ch = fmaxf(cy2 - cy1, 0.f);
    float ac = cw * ch;
    return iou - (ac - uni) / fmaxf(ac, 1e-6f);
}

__device__ __forceinline__ unsigned ord_map(float f) {
    unsigned u = __float_as_uint(f);
    return (u & 0x80000000u) ? ~u : (u | 0x80000000u);   // order-preserving map
}

// ---- K1: per-query softmax + PACKED transposed ord write (+ acc reset) ----
// 4 waves = 4 consecutive queries of ONE batch (900 = 4*225, no straddle).
// LDS exchange (4x30 u32) -> threads 0..29 store uint4 {4 rows x col t}:
// 30 packed 16B stores/block (432K total) vs scalar scatter's 1.73M requests.
__global__ __launch_bounds__(256) void cost_kernel(const float* __restrict__ logits,
                                                   const float* __restrict__ pboxes,
                                                   const int*   __restrict__ labels,
                                                   const float* __restrict__ tboxes) {
    if (blockIdx.x == 0 && threadIdx.x == 0) {
        g_acc[0] = 0.f; g_acc[1] = 0.f; g_acc[2] = 0.f;
        g_cnt = 0u;
    }
    int tid = threadIdx.x;
    int lane = tid & 63, wid = tid >> 6;
    int gwave = blockIdx.x * 4 + wid;          // query index (grid exact: 14400*4)
    int b = gwave / QQ;

    __shared__ unsigned s_c[4][NN];            // 480 B exchange buffer

    size_t s = (size_t)gwave * C1;
    size_t a0 = (s + 3) >> 2;
    size_t a1 = (s + C1) >> 2;
    int nq = (int)(a1 - a0);
    int hh = (int)(a0 * 4 - s);
    int tt = (int)((s + C1) - a1 * 4);
    const float4* L4 = (const float4*)logits;

    float4 v4[4];
#pragma unroll
    for (int i = 0; i < 4; ++i) {
        int qq = lane + 64 * i;
        v4[i] = (qq < nq) ? L4[a0 + qq]
                          : make_float4(-INFINITY, -INFINITY, -INFINITY, -INFINITY);
    }
    float e1 = (lane < hh) ? logits[s + lane] : -INFINITY;
    float e2 = (lane < tt) ? logits[a1 * 4 + lane] : -INFINITY;

    float mx = fmaxf(e1, e2);
#pragma unroll
    for (int i = 0; i < 4; ++i)
        mx = fmaxf(mx, fmaxf(fmaxf(v4[i].x, v4[i].y), fmaxf(v4[i].z, v4[i].w)));
#pragma unroll
    for (int off = 32; off; off >>= 1) mx = fmaxf(mx, __shfl_xor(mx, off));

    float sm = __expf(e1 - mx) + __expf(e2 - mx);
#pragma unroll
    for (int i = 0; i < 4; ++i) {
        sm += __expf(v4[i].x - mx);
        sm += __expf(v4[i].y - mx);
        sm += __expf(v4[i].z - mx);
        sm += __expf(v4[i].w - mx);
    }
#pragma unroll
    for (int off = 32; off; off >>= 1) sm += __shfl_xor(sm, off);
    float logZ = mx + __logf(sm);

    float row1000 = logits[s + 1000];

    const float* pb = pboxes + (size_t)gwave * 4;
    float cx = pb[0], cy = pb[1], w = pb[2], h = pb[3];
    float x1 = fminf(fmaxf(cx - 0.5f * w, 0.f), 1.f);
    float y1 = fminf(fmaxf(cy - 0.5f * h, 0.f), 1.f);
    float x2 = fminf(fmaxf(cx + 0.5f * w, 0.f), 1.f);
    float y2 = fminf(fmaxf(cy + 0.5f * h, 0.f), 1.f);

    if (lane == 0) {
        g_logZ[gwave] = logZ;
        g_noobj[gwave] = logZ - row1000;
        g_xyxy[gwave] = make_float4(x1, y1, x2, y2);
    }

    if (lane < NN) {
        int t = lane;
        int lab = labels[b * NN + t];
        float pcls = __expf(logits[s + lab] - logZ);
        const float* tb = tboxes + ((size_t)(b * NN + t)) * 4;
        float tx1 = tb[0], ty1 = tb[1], tx2 = tb[2], ty2 = tb[3];
        float l1 = fabsf(x1 - tx1) + fabsf(y1 - ty1) + fabsf(x2 - tx2) + fabsf(y2 - ty2);
        float g = giou_f(x1, y1, x2, y2, tx1, ty1, tx2, ty2);
        s_c[wid][t] = ord_map(-pcls + 5.0f * l1 - 2.0f * g);
    }
    __syncthreads();

    if (tid < NN) {                             // packed transposed store
        int t = tid;
        int q0 = (blockIdx.x % 225) * 4;        // first of the block's 4 queries
        int b0 = blockIdx.x / 225;
        uint4 v = make_uint4(s_c[0][t], s_c[1][t], s_c[2][t], s_c[3][t]);
        *(uint4*)&g_ordT[((size_t)(b0 * NN + t)) * QQ + q0] = v;   // 16B-aligned
    }
}

// ---- K2: per-column sorted top-30, COALESCED reads (one wave per (b,t)) ----
__global__ __launch_bounds__(256) void select_kernel() {
    int gw = (blockIdx.x * blockDim.x + threadIdx.x) >> 6;   // (b,t) = gw
    int lane = threadIdx.x & 63;
    if (gw >= BB * NN) return;
    int t = gw % NN;

    const unsigned* col = g_ordT + (size_t)gw * QQ;   // contiguous column!
    unsigned long long key[16];
#pragma unroll
    for (int j = 0; j < 15; ++j) {
        int q = j * 64 + lane;                 // lane stride 4B -> coalesced
        if (q < QQ) {
            unsigned o = col[q];
            key[j] = ((unsigned long long)o << 32) | (unsigned)(q * NN + t);
        } else {
            key[j] = ~0ull;
        }
    }
    key[15] = ~0ull;

    // bitonic sort 16 ascending, fully static indices
#pragma unroll
    for (int kk = 2; kk <= 16; kk <<= 1) {
#pragma unroll
        for (int jj = kk >> 1; jj > 0; jj >>= 1) {
#pragma unroll
            for (int i = 0; i < 16; ++i) {
                int l = i ^ jj;
                if (l > i) {
                    bool up = ((i & kk) == 0);
                    unsigned long long a = key[i], c = key[l];
                    bool sw = up ? (a > c) : (a < c);
                    key[i] = sw ? c : a;
                    key[l] = sw ? a : c;
                }
            }
        }
    }

    unsigned long long* outp = g_top + (size_t)gw * NN;
#pragma unroll 1
    for (int r = 0; r < NN / 2; ++r) {         // pop-2 per round: 15 rounds
        unsigned long long m1 = key[0];
        unsigned long long m2 = key[1];
#pragma unroll
        for (int off = 32; off; off >>= 1) {
            unsigned long long o1 = __shfl_xor(m1, off);
            unsigned long long o2 = __shfl_xor(m2, off);
            unsigned long long lo = (o1 < m1) ? o1 : m1;
            unsigned long long hi = (o1 < m1) ? m1 : o1;
            unsigned long long n2 = (o2 < m2) ? o2 : m2;
            m1 = lo;
            m2 = (hi < n2) ? hi : n2;
        }
        if (lane == 2 * r)     outp[2 * r]     = m1;   // sorted ascending
        if (lane == 2 * r + 1) outp[2 * r + 1] = m2;
        if (key[0] == m1 || key[0] == m2) {
#pragma unroll
            for (int j = 0; j < 15; ++j) key[j] = key[j + 1];
            key[15] = ~0ull;
        }
        if (key[0] == m2) {
#pragma unroll
            for (int j = 0; j < 15; ++j) key[j] = key[j + 1];
            key[15] = ~0ull;
        }
    }
}

// ---- K3: fused greedy match (pop-1-or-2) + losses + global reduce ----
__global__ __launch_bounds__(256) void match_loss_kernel(const float* __restrict__ logits,
                                                         const int*   __restrict__ labels,
                                                         const float* __restrict__ tboxes,
                                                         float* __restrict__ out) {
    int b = blockIdx.x;
    int tid = threadIdx.x;

    __shared__ unsigned long long s_cand[NN * NN];   // 7.2 KB
    __shared__ int s_pi[NN], s_ti[NN];
    __shared__ unsigned s_dead[29];
    __shared__ float s4[4][4];

    const unsigned long long* topb = g_top + (size_t)b * NN * NN;
    for (int i = tid; i < NN * NN; i += 256) s_cand[i] = topb[i];
    if (tid < 29) s_dead[tid] = 0u;
    __syncthreads();

    if (tid < 64) {   // wave 0: greedy match on 30 sorted candidate lists
        int lane = tid;
        bool colLive = lane < NN;
        int ptr = 0;
        unsigned long long cand = colLive ? s_cand[lane * NN] : ~0ull;
        unsigned rowc = colLive ? ((unsigned)cand) / NN : 0u;

        int it = 0;
        while (it < NN) {
            unsigned long long m1 = colLive ? cand : ~0ull;
            unsigned long long m2 = ~0ull;
#pragma unroll
            for (int off = 32; off; off >>= 1) {
                unsigned long long o1 = __shfl_xor(m1, off);
                unsigned long long o2 = __shfl_xor(m2, off);
                unsigned long long lo = (o1 < m1) ? o1 : m1;
                unsigned long long hi = (o1 < m1) ? m1 : o1;
                unsigned long long n2 = (o2 < m2) ? o2 : m2;
                m1 = lo;
                m2 = (hi < n2) ? hi : n2;
            }
            unsigned e1 = (unsigned)m1;
            int q1 = e1 / NN, t1 = e1 - (e1 / NN) * NN;
            unsigned e2 = (unsigned)m2;
            int q2 = e2 / NN, t2 = e2 - (e2 / NN) * NN;
            bool acc2 = (m2 != ~0ull) && (it + 1 < NN) && (q2 != q1) && (t2 != t1);

            if (lane == 0) {
                s_pi[it] = q1;
                s_ti[it] = t1;
                s_dead[q1 >> 5] |= (1u << (q1 & 31));
                if (acc2) {
                    s_pi[it + 1] = q2;
                    s_ti[it + 1] = t2;
                    s_dead[q2 >> 5] |= (1u << (q2 & 31));
                }
            }
            if (lane == t1) colLive = false;
            if (acc2 && lane == t2) colLive = false;
            if (colLive && (rowc == (unsigned)q1 || (acc2 && rowc == (unsigned)q2))) {
                do {
                    ++ptr;
                    cand = s_cand[lane * NN + ptr];
                    rowc = ((unsigned)cand) / NN;
                } while ((s_dead[rowc >> 5] >> (rowc & 31)) & 1u);
            }
            it += acc2 ? 2 : 1;
        }
    }
    __syncthreads();

    // loss phase (CE algebra: per-batch denom == 117 exactly)
    float sA = 0.f;
    for (int q = tid; q < QQ; q += 256) sA += g_noobj[b * QQ + q];

    float sB = 0.f, sL = 0.f, sG = 0.f;
    if (tid < NN) {
        int pq = s_pi[tid], pt = s_ti[tid];
        int gq = b * QQ + pq;
        int lab = labels[b * NN + pt];
        float mnll = g_logZ[gq] - logits[(size_t)gq * C1 + lab];
        sB = mnll - NO_OBJ_W * g_noobj[gq];
        float4 p = g_xyxy[gq];
        const float* tb = tboxes + ((size_t)(b * NN + pt)) * 4;
        float tx1 = tb[0], ty1 = tb[1], tx2 = tb[2], ty2 = tb[3];
        sL = fabsf(p.x - tx1) + fabsf(p.y - ty1) + fabsf(p.z - tx2) + fabsf(p.w - ty2);
        sG = 1.0f - giou_f(p.x, p.y, p.z, p.w, tx1, ty1, tx2, ty2);
    }

    int lane = tid & 63, wid = tid >> 6;
    float vv[4] = {sA, sB, sL, sG};
#pragma unroll
    for (int j = 0; j < 4; ++j) {
        float x = vv[j];
#pragma unroll
        for (int off = 32; off; off >>= 1) x += __shfl_xor(x, off);
        if (lane == 0) s4[wid][j] = x;
    }
    __syncthreads();
    if (tid == 0) {
        float a = 0.f, bs = 0.f, l = 0.f, g = 0.f;
        for (int w = 0; w < 4; ++w) { a += s4[w][0]; bs += s4[w][1]; l += s4[w][2]; g += s4[w][3]; }
        atomicAdd(&g_acc[0], NO_OBJ_W * a + bs);
        atomicAdd(&g_acc[1], l);
        atomicAdd(&g_acc[2], g);
        __threadfence();
        unsigned prev = atomicAdd(&g_cnt, 1u);
        if (prev == BB - 1) {   // last block finalizes
            __threadfence();
            float ce = atomicAdd(&g_acc[0], 0.f) / (float)(BB * 117);
            float l1 = atomicAdd(&g_acc[1], 0.f) / (float)(BB * NN * 4);
            float gl = atomicAdd(&g_acc[2], 0.f) / (float)(BB * NN);
            out[0] = ce + 5.0f * l1 + 2.0f * gl;
            out[1] = ce;
            out[2] = l1;
            out[3] = gl;
        }
    }
}

extern "C" void kernel_launch(void* const* d_in, const int* in_sizes, int n_in,
                              void* d_out, int out_size, void* d_ws, size_t ws_size,
                              hipStream_t stream) {
    const float* pred_logits = (const float*)d_in[0];
    const float* pred_boxes  = (const float*)d_in[1];
    const int*   tgt_labels  = (const int*)d_in[2];
    const float* tgt_boxes   = (const float*)d_in[3];
    float* out = (float*)d_out;

    cost_kernel<<<(BB * QQ) / 4, 256, 0, stream>>>(pred_logits, pred_boxes, tgt_labels, tgt_boxes);
    select_kernel<<<(BB * NN) / 4, 256, 0, stream>>>();
    match_loss_kernel<<<BB, 256, 0, stream>>>(pred_logits, tgt_labels, tgt_boxes, out);
}